// Round 5
// baseline (497.094 us; speedup 1.0000x reference)
//
#include <hip/hip_runtime.h>
#include <math.h>

#define NN 2048
#define NH 16
#define HSZ 32
#define INF_ 256
#define NBLK 256
#define NTHR 256
#define NTOT (NBLK * NTHR)
#define DOOR_MAGIC 0x1357bd1

struct Params {
    const float *x, *W1, *al1, *ar1, *bg1, *W2, *al2, *ar2, *bg2;
    const float *qw, *qb, *kw, *kb, *vw, *vb, *ow, *ob;
    const float *bn_g, *bn_b, *m1w, *m1b, *m2w, *m2b;
    const float *w001, *b001, *w01, *b01, *w1v, *b1v, *w2v, *b2v;
    const int *src, *dst;
    float *feat, *el, *er, *ssumA, *accA, *ssumB, *accB, *bnbuf;
    float *Q, *Kt, *Vt, *X, *out;
    int *bar;  // [0..5] phase counters, [7] doorbell
    int E;
};

// device-scope grid barrier: counter per phase, doorbell-gated first arrival.
// 256 blocks <= 256 CUs with launch_bounds(256,1) => all blocks co-resident.
__device__ __forceinline__ void gbar(int* __restrict__ bar, int slot, bool first) {
    __threadfence();   // release: make this block's writes agent-visible
    __syncthreads();
    if (threadIdx.x == 0) {
        if (first) {   // wait for block 0 to have zeroed the counters
            while (__hip_atomic_load(&bar[7], __ATOMIC_ACQUIRE,
                                     __HIP_MEMORY_SCOPE_AGENT) != DOOR_MAGIC)
                __builtin_amdgcn_s_sleep(2);
        }
        __hip_atomic_fetch_add(&bar[slot], 1, __ATOMIC_ACQ_REL,
                               __HIP_MEMORY_SCOPE_AGENT);
        while (__hip_atomic_load(&bar[slot], __ATOMIC_ACQUIRE,
                                 __HIP_MEMORY_SCOPE_AGENT) < NBLK)
            __builtin_amdgcn_s_sleep(2);
    }
    __syncthreads();
    __threadfence();   // acquire: invalidate stale cached lines
}

// edge softmax-accumulate: thread per (edge,head), grid-stride
__device__ __forceinline__ void edge_phase(const int* __restrict__ src,
                                           const int* __restrict__ dst,
                                           const float* __restrict__ el,
                                           const float* __restrict__ er,
                                           const float* __restrict__ feat,
                                           float* __restrict__ ssum,
                                           float* __restrict__ acc, int E, int gtid) {
    int EH = E * NH;
    for (int i = gtid; i < EH; i += NTOT) {
        int e = i >> 4, h = i & 15;
        int s = src[e], d = dst[e];
        float v = el[s * NH + h] + er[d * NH + h];
        v = v > 0.f ? v : 0.2f * v;
        float ex = __expf(v);
        float2 f = ((const float2*)feat)[s * NH + h];
        atomicAdd(&ssum[d * NH + h], ex);
        atomicAdd(&acc[(d * NH + h) * 2 + 0], ex * f.x);
        atomicAdd(&acc[(d * NH + h) * 2 + 1], ex * f.y);
    }
}

// normalize prev layer -> h (8 rows/block in LDS) -> feat/el/er of next layer
__device__ __forceinline__ void gat_phase(const float* __restrict__ acc,
                                          const float* __restrict__ ssum,
                                          const float* __restrict__ bias,
                                          const float* __restrict__ W,
                                          const float* __restrict__ al,
                                          const float* __restrict__ ar,
                                          float* __restrict__ feat, float* __restrict__ el,
                                          float* __restrict__ er, float* shA, float* shB,
                                          int blk, int tid) {
    int r = tid >> 5, j = tid & 31;
    int row0 = blk * 8;
    int n = row0 + r;
    shA[tid] = acc[n * HSZ + j] / ssum[n * NH + (j >> 1)] + bias[j];
    __syncthreads();
    float a = 0.f;
#pragma unroll
    for (int c = 0; c < HSZ; ++c) a += shA[r * HSZ + c] * W[c * HSZ + j];
    shB[tid] = a;
    feat[row0 * HSZ + tid] = a;
    __syncthreads();
    if (tid < 128) {
        int rr = tid >> 4, hh = tid & 15;
        el[(row0 + rr) * NH + hh] =
            shB[rr * HSZ + 2 * hh] * al[2 * hh] + shB[rr * HSZ + 2 * hh + 1] * al[2 * hh + 1];
    } else {
        int t = tid - 128, rr = t >> 4, hh = t & 15;
        er[(row0 + rr) * NH + hh] =
            shB[rr * HSZ + 2 * hh] * ar[2 * hh] + shB[rr * HSZ + 2 * hh + 1] * ar[2 * hh + 1];
    }
    __syncthreads();
}

__global__ void __launch_bounds__(NTHR, 1) mega(Params p) {
    __shared__ float shA[256];
    __shared__ float shB[256];
    const int tid = threadIdx.x;
    const int blk = blockIdx.x;
    const int gtid = blk * NTHR + tid;

    // ---- barrier init (block 0) + doorbell release ----
    if (blk == 0) {
        if (tid < 7)
            __hip_atomic_store(&p.bar[tid], 0, __ATOMIC_RELAXED,
                               __HIP_MEMORY_SCOPE_AGENT);
        __threadfence();
        __syncthreads();
        if (tid == 0)
            __hip_atomic_store(&p.bar[7], DOOR_MAGIC, __ATOMIC_RELEASE,
                               __HIP_MEMORY_SCOPE_AGENT);
    }

    // ---- P0: zero accumulators (ssumA..accB..bnbuf contiguous) + GAT1 feats ----
    {
        float* z = p.ssumA;
        const int ztot = NN * 96 + 64;
        for (int i = gtid; i < ztot; i += NTOT) z[i] = 0.f;
    }
    {
        int j = tid & 31, part = tid >> 5;
        for (int r = 0; r < 8; ++r) {
            int n = blk * 8 + r;
            shA[tid] = p.x[(size_t)n * INF_ + tid];
            __syncthreads();
            float a = 0.f;
#pragma unroll
            for (int kk = 0; kk < 32; ++kk) {
                int k = part * 32 + kk;
                a += shA[k] * p.W1[k * HSZ + j];
            }
            shB[tid] = a;
            __syncthreads();
            if (tid < HSZ) {
                float s = 0.f;
#pragma unroll
                for (int q = 0; q < 8; ++q) s += shB[q * 32 + tid];
                p.feat[n * HSZ + tid] = s;
                shA[tid] = s;  // fs for el/er
            }
            __syncthreads();
            if (tid < NH) {
                p.el[n * NH + tid] =
                    shA[2 * tid] * p.al1[2 * tid] + shA[2 * tid + 1] * p.al1[2 * tid + 1];
            } else if (tid < 2 * NH) {
                int hh = tid - NH;
                p.er[n * NH + hh] =
                    shA[2 * hh] * p.ar1[2 * hh] + shA[2 * hh + 1] * p.ar1[2 * hh + 1];
            }
            __syncthreads();
        }
    }
    gbar(p.bar, 0, true);

    // ---- P1: edge accumulate, layer 1 ----
    edge_phase(p.src, p.dst, p.el, p.er, p.feat, p.ssumA, p.accA, p.E, gtid);
    gbar(p.bar, 1, false);

    // ---- P2: h1 -> GAT2 feats ----
    gat_phase(p.accA, p.ssumA, p.bg1, p.W2, p.al2, p.ar2, p.feat, p.el, p.er, shA, shB,
              blk, tid);
    gbar(p.bar, 2, false);

    // ---- P3: edge accumulate, layer 2 ----
    edge_phase(p.src, p.dst, p.el, p.er, p.feat, p.ssumB, p.accB, p.E, gtid);
    gbar(p.bar, 3, false);

    // ---- P4: h2 -> QKV (Q pre-scaled by 1/sqrt(2); K,V in [H][N][2]) ----
    {
        int r = tid >> 5, j = tid & 31;
        int row0 = blk * 8;
        int n = row0 + r;
        shA[tid] = p.accB[n * HSZ + j] / p.ssumB[n * NH + (j >> 1)] + p.bg2[j];
        __syncthreads();
        float q = p.qb[j], k = p.kb[j], v = p.vb[j];
#pragma unroll
        for (int c = 0; c < HSZ; ++c) {
            float hv = shA[r * HSZ + c];
            q += hv * p.qw[c * HSZ + j];
            k += hv * p.kw[c * HSZ + j];
            v += hv * p.vw[c * HSZ + j];
        }
        p.Q[n * HSZ + j] = q * 0.70710678118654752f;
        int hh = j >> 1, d2 = j & 1;
        p.Kt[hh * (NN * 2) + n * 2 + d2] = k;
        p.Vt[hh * (NN * 2) + n * 2 + d2] = v;
        __syncthreads();
    }
    gbar(p.bar, 4, false);

    // ---- P5: attention (wave per head, 8 queries) + O-proj + BN partials ----
    {
        int wave = tid >> 6, lane = tid & 63;
        int row0 = blk * 8;
        for (int h = wave; h < NH; h += 4) {
            float qx[8], qy[8];
#pragma unroll
            for (int i = 0; i < 8; ++i) {
                float2 qq = ((const float2*)p.Q)[(row0 + i) * NH + h];
                qx[i] = qq.x;
                qy[i] = qq.y;
            }
            const float2* K2 = (const float2*)p.Kt + h * NN;
            const float2* V2 = (const float2*)p.Vt + h * NN;
            float sm[8], a0[8], a1[8];
#pragma unroll
            for (int i = 0; i < 8; ++i) { sm[i] = 0.f; a0[i] = 0.f; a1[i] = 0.f; }
#pragma unroll 2
            for (int it = 0; it < NN / 64; ++it) {
                float2 kk = K2[it * 64 + lane];
                float2 vv = V2[it * 64 + lane];
#pragma unroll
                for (int i = 0; i < 8; ++i) {
                    float pp = __expf(qx[i] * kk.x + qy[i] * kk.y);
                    sm[i] += pp;
                    a0[i] += pp * vv.x;
                    a1[i] += pp * vv.y;
                }
            }
#pragma unroll
            for (int i = 0; i < 8; ++i) {
#pragma unroll
                for (int off = 32; off > 0; off >>= 1) {
                    sm[i] += __shfl_xor(sm[i], off);
                    a0[i] += __shfl_xor(a0[i], off);
                    a1[i] += __shfl_xor(a1[i], off);
                }
                if (lane == 0) {
                    float rs = 1.f / sm[i];
                    shA[i * HSZ + 2 * h] = a0[i] * rs;
                    shA[i * HSZ + 2 * h + 1] = a1[i] * rs;
                }
            }
        }
        __syncthreads();
        // O-projection on the block's 8 rows (ao never left LDS)
        int r = tid >> 5, j = tid & 31;
        float a = p.ob[j];
#pragma unroll
        for (int c = 0; c < HSZ; ++c) a += shA[r * HSZ + c] * p.ow[c * HSZ + j];
        p.X[(row0 + r) * HSZ + j] = a;
        shB[tid] = a;
        __syncthreads();
        if (tid < HSZ) {
            float s = 0.f, q = 0.f;
#pragma unroll
            for (int rr = 0; rr < 8; ++rr) {
                float v = shB[rr * HSZ + tid];
                s += v;
                q += v * v;
            }
            atomicAdd(&p.bnbuf[tid], s);
            atomicAdd(&p.bnbuf[HSZ + tid], q);
        }
    }
    gbar(p.bar, 5, false);

    // ---- P6: BN apply + MLP + scoring head + sigmoid ----
    if (gtid < NN) {
        int n = gtid;
        const float invN = 1.f / NN;
        float xr[HSZ];
#pragma unroll
        for (int i = 0; i < HSZ; ++i) {
            float mu = p.bnbuf[i] * invN;
            float var = p.bnbuf[HSZ + i] * invN - mu * mu;
            float rstd = rsqrtf(var + 1e-5f);
            xr[i] = (p.X[n * HSZ + i] - mu) * rstd * p.bn_g[i] + p.bn_b[i];
        }
        float y[16];
#pragma unroll
        for (int j = 0; j < 16; ++j) {
            float a = p.m1b[j];
#pragma unroll
            for (int i = 0; i < HSZ; ++i) a += xr[i] * p.m1w[i * 16 + j];
            y[j] = fmaxf(a, 0.f);
        }
        float z[HSZ];
#pragma unroll
        for (int j = 0; j < HSZ; ++j) {
            float a = p.m2b[j];
#pragma unroll
            for (int i = 0; i < 16; ++i) a += y[i] * p.m2w[i * HSZ + j];
            z[j] = fmaxf(a, 0.f);
        }
        float a16[16];
#pragma unroll
        for (int j = 0; j < 16; ++j) {
            float a = p.b001[j];
#pragma unroll
            for (int i = 0; i < HSZ; ++i) a += z[i] * p.w001[i * 16 + j];
            a16[j] = a > 0.f ? a : 0.01f * a;
        }
        float b8[8];
#pragma unroll
        for (int j = 0; j < 8; ++j) {
            float a = p.b01[j];
#pragma unroll
            for (int i = 0; i < 16; ++i) a += a16[i] * p.w01[i * 8 + j];
            b8[j] = a > 0.f ? a : 0.01f * a;
        }
        float c4[4];
#pragma unroll
        for (int j = 0; j < 4; ++j) {
            float a = p.b1v[j];
#pragma unroll
            for (int i = 0; i < 8; ++i) a += b8[i] * p.w1v[i * 4 + j];
            c4[j] = a > 0.f ? a : 0.01f * a;
        }
        float d = p.b2v[0];
#pragma unroll
        for (int i = 0; i < 4; ++i) d += c4[i] * p.w2v[i];
        p.out[n] = 1.f / (1.f + __expf(-d));
    }
}

extern "C" void kernel_launch(void* const* d_in, const int* in_sizes, int n_in,
                              void* d_out, int out_size, void* d_ws, size_t ws_size,
                              hipStream_t stream) {
    Params p;
    p.x = (const float*)d_in[0];
    p.src = (const int*)d_in[1];
    p.dst = (const int*)d_in[2];
    p.W1 = (const float*)d_in[3];
    p.al1 = (const float*)d_in[4];
    p.ar1 = (const float*)d_in[5];
    p.bg1 = (const float*)d_in[6];
    p.W2 = (const float*)d_in[7];
    p.al2 = (const float*)d_in[8];
    p.ar2 = (const float*)d_in[9];
    p.bg2 = (const float*)d_in[10];
    p.qw = (const float*)d_in[11];
    p.qb = (const float*)d_in[12];
    p.kw = (const float*)d_in[13];
    p.kb = (const float*)d_in[14];
    p.vw = (const float*)d_in[15];
    p.vb = (const float*)d_in[16];
    p.ow = (const float*)d_in[17];
    p.ob = (const float*)d_in[18];
    p.bn_g = (const float*)d_in[19];
    p.bn_b = (const float*)d_in[20];
    p.m1w = (const float*)d_in[21];
    p.m1b = (const float*)d_in[22];
    p.m2w = (const float*)d_in[23];
    p.m2b = (const float*)d_in[24];
    p.w001 = (const float*)d_in[25];
    p.b001 = (const float*)d_in[26];
    p.w01 = (const float*)d_in[27];
    p.b01 = (const float*)d_in[28];
    p.w1v = (const float*)d_in[29];
    p.b1v = (const float*)d_in[30];
    p.w2v = (const float*)d_in[31];
    p.b2v = (const float*)d_in[32];
    p.E = in_sizes[1];

    float* ws = (float*)d_ws;
    p.feat = ws;                       // NN*32
    p.el = p.feat + NN * HSZ;          // NN*16
    p.er = p.el + NN * NH;             // NN*16
    p.ssumA = p.er + NN * NH;          // NN*16 ┐ zeroed as one
    p.accA = p.ssumA + NN * NH;        // NN*32 │ contiguous
    p.ssumB = p.accA + NN * HSZ;       // NN*16 │ region in P0
    p.accB = p.ssumB + NN * NH;        // NN*32 │
    p.bnbuf = p.accB + NN * HSZ;       // 64    ┘
    p.Q = p.bnbuf + 64;                // NN*32
    p.Kt = p.Q + NN * HSZ;             // NN*32
    p.Vt = p.Kt + NN * HSZ;            // NN*32
    p.X = p.Vt + NN * HSZ;             // NN*32
    p.bar = (int*)(p.X + NN * HSZ);    // 8 ints
    p.out = (float*)d_out;

    mega<<<dim3(NBLK), dim3(NTHR), 0, stream>>>(p);
}

// Round 6
// 391.595 us; speedup vs baseline: 1.2694x; 1.2694x over previous
//
#include <hip/hip_runtime.h>
#include <math.h>

#define NN 2048
#define NH 16
#define HSZ 32
#define INF_ 256
#define NBLK 256
#define NTHR 256
#define NTOT (NBLK * NTHR)
#define DOOR_MAGIC 0x1357bd1

struct Params {
    const float *x, *W1, *al1, *ar1, *bg1, *W2, *al2, *ar2, *bg2;
    const float *qw, *qb, *kw, *kb, *vw, *vb, *ow, *ob;
    const float *bn_g, *bn_b, *m1w, *m1b, *m2w, *m2b;
    const float *w001, *b001, *w01, *b01, *w1v, *b1v, *w2v, *b2v;
    const int *src, *dst;
    float *feat, *el, *er, *ssumA, *accA, *ssumB, *accB, *bnbuf;
    float *Q, *Kt, *Vt, *out;
    int *bar;  // bar[0]=count, bar[32]=flag, bar[64]=doorbell (separate 128B lines)
    int E;
};

// Grid barrier, ockl-style: arrivals RMW bar[0]; pollers spin READ-ONLY and
// RELAXED on bar[32] (different cache line -> no ownership ping-pong with the
// RMWs); last block resets count then release-stores flag=phase. Data
// visibility via __threadfence() executed by ALL threads on both sides.
__device__ __forceinline__ void gbar(int* bar, int phase, bool first) {
    __threadfence();  // release side
    __syncthreads();
    if (threadIdx.x == 0) {
        if (first) {  // wait for block 0 to have initialized count/flag
            while (__hip_atomic_load(&bar[64], __ATOMIC_RELAXED,
                                     __HIP_MEMORY_SCOPE_AGENT) != DOOR_MAGIC)
                __builtin_amdgcn_s_sleep(8);
        }
        int old = __hip_atomic_fetch_add(&bar[0], 1, __ATOMIC_RELAXED,
                                         __HIP_MEMORY_SCOPE_AGENT);
        if (old == NBLK - 1) {
            __hip_atomic_store(&bar[0], 0, __ATOMIC_RELAXED,
                               __HIP_MEMORY_SCOPE_AGENT);
            __hip_atomic_store(&bar[32], phase, __ATOMIC_RELEASE,
                               __HIP_MEMORY_SCOPE_AGENT);
        } else {
            while (__hip_atomic_load(&bar[32], __ATOMIC_RELAXED,
                                     __HIP_MEMORY_SCOPE_AGENT) < phase)
                __builtin_amdgcn_s_sleep(8);
        }
    }
    __syncthreads();
    __threadfence();  // acquire side
}

// edge softmax-accumulate: thread per (edge,head), grid-stride
__device__ __forceinline__ void edge_phase(const int* __restrict__ src,
                                           const int* __restrict__ dst,
                                           const float* __restrict__ el,
                                           const float* __restrict__ er,
                                           const float* __restrict__ feat,
                                           float* __restrict__ ssum,
                                           float* __restrict__ acc, int E, int gtid) {
    int EH = E * NH;
    for (int i = gtid; i < EH; i += NTOT) {
        int e = i >> 4, h = i & 15;
        int s = src[e], d = dst[e];
        float v = el[s * NH + h] + er[d * NH + h];
        v = v > 0.f ? v : 0.2f * v;
        float ex = __expf(v);
        float2 f = ((const float2*)feat)[s * NH + h];
        atomicAdd(&ssum[d * NH + h], ex);
        atomicAdd(&acc[(d * NH + h) * 2 + 0], ex * f.x);
        atomicAdd(&acc[(d * NH + h) * 2 + 1], ex * f.y);
    }
}

// normalize prev layer -> h (8 rows/block in LDS) -> feat/el/er of next layer
__device__ __forceinline__ void gat_phase(const float* __restrict__ acc,
                                          const float* __restrict__ ssum,
                                          const float* __restrict__ bias,
                                          const float* __restrict__ W,
                                          const float* __restrict__ al,
                                          const float* __restrict__ ar,
                                          float* __restrict__ feat, float* __restrict__ el,
                                          float* __restrict__ er, float* shA, float* shB,
                                          int blk, int tid) {
    int r = tid >> 5, j = tid & 31;
    int row0 = blk * 8;
    int n = row0 + r;
    shA[tid] = acc[n * HSZ + j] / ssum[n * NH + (j >> 1)] + bias[j];
    __syncthreads();
    float a = 0.f;
#pragma unroll
    for (int c = 0; c < HSZ; ++c) a += shA[r * HSZ + c] * W[c * HSZ + j];
    shB[tid] = a;
    feat[row0 * HSZ + tid] = a;
    __syncthreads();
    if (tid < 128) {
        int rr = tid >> 4, hh = tid & 15;
        el[(row0 + rr) * NH + hh] =
            shB[rr * HSZ + 2 * hh] * al[2 * hh] + shB[rr * HSZ + 2 * hh + 1] * al[2 * hh + 1];
    } else {
        int t = tid - 128, rr = t >> 4, hh = t & 15;
        er[(row0 + rr) * NH + hh] =
            shB[rr * HSZ + 2 * hh] * ar[2 * hh] + shB[rr * HSZ + 2 * hh + 1] * ar[2 * hh + 1];
    }
    __syncthreads();
}

__global__ void __launch_bounds__(NTHR, 1) mega(Params p) {
    __shared__ float shA[256];
    __shared__ float shB[256];
    const int tid = threadIdx.x;
    const int blk = blockIdx.x;
    const int gtid = blk * NTHR + tid;

    // ---- barrier init (block 0, single thread; doorbell released last) ----
    if (blk == 0 && tid == 0) {
        __hip_atomic_store(&p.bar[0], 0, __ATOMIC_RELAXED, __HIP_MEMORY_SCOPE_AGENT);
        __hip_atomic_store(&p.bar[32], 0, __ATOMIC_RELAXED, __HIP_MEMORY_SCOPE_AGENT);
        __hip_atomic_store(&p.bar[64], DOOR_MAGIC, __ATOMIC_RELEASE,
                           __HIP_MEMORY_SCOPE_AGENT);
    }

    // ---- P0: zero accumulators (ssumA..accB..bnbuf contiguous) + GAT1 feats ----
    {
        float* z = p.ssumA;
        const int ztot = NN * 96 + 64;
        for (int i = gtid; i < ztot; i += NTOT) z[i] = 0.f;
    }
    {
        int j = tid & 31, part = tid >> 5;
        for (int r = 0; r < 8; ++r) {
            int n = blk * 8 + r;
            shA[tid] = p.x[(size_t)n * INF_ + tid];
            __syncthreads();
            float a = 0.f;
#pragma unroll
            for (int kk = 0; kk < 32; ++kk) {
                int k = part * 32 + kk;
                a += shA[k] * p.W1[k * HSZ + j];
            }
            shB[tid] = a;
            __syncthreads();
            if (tid < HSZ) {
                float s = 0.f;
#pragma unroll
                for (int q = 0; q < 8; ++q) s += shB[q * 32 + tid];
                p.feat[n * HSZ + tid] = s;
                shA[tid] = s;  // fs for el/er
            }
            __syncthreads();
            if (tid < NH) {
                p.el[n * NH + tid] =
                    shA[2 * tid] * p.al1[2 * tid] + shA[2 * tid + 1] * p.al1[2 * tid + 1];
            } else if (tid < 2 * NH) {
                int hh = tid - NH;
                p.er[n * NH + hh] =
                    shA[2 * hh] * p.ar1[2 * hh] + shA[2 * hh + 1] * p.ar1[2 * hh + 1];
            }
            __syncthreads();
        }
    }
    gbar(p.bar, 1, true);

    // ---- P1: edge accumulate, layer 1 ----
    edge_phase(p.src, p.dst, p.el, p.er, p.feat, p.ssumA, p.accA, p.E, gtid);
    gbar(p.bar, 2, false);

    // ---- P2: h1 -> GAT2 feats ----
    gat_phase(p.accA, p.ssumA, p.bg1, p.W2, p.al2, p.ar2, p.feat, p.el, p.er, shA, shB,
              blk, tid);
    gbar(p.bar, 3, false);

    // ---- P3: edge accumulate, layer 2 ----
    edge_phase(p.src, p.dst, p.el, p.er, p.feat, p.ssumB, p.accB, p.E, gtid);
    gbar(p.bar, 4, false);

    // ---- P4: h2 -> QKV (Q pre-scaled by 1/sqrt(2); K,V in [H][N][2]) ----
    {
        int r = tid >> 5, j = tid & 31;
        int row0 = blk * 8;
        int n = row0 + r;
        shA[tid] = p.accB[n * HSZ + j] / p.ssumB[n * NH + (j >> 1)] + p.bg2[j];
        __syncthreads();
        float q = p.qb[j], k = p.kb[j], v = p.vb[j];
#pragma unroll
        for (int c = 0; c < HSZ; ++c) {
            float hv = shA[r * HSZ + c];
            q += hv * p.qw[c * HSZ + j];
            k += hv * p.kw[c * HSZ + j];
            v += hv * p.vw[c * HSZ + j];
        }
        p.Q[n * HSZ + j] = q * 0.70710678118654752f;
        int hh = j >> 1, d2 = j & 1;
        p.Kt[hh * (NN * 2) + n * 2 + d2] = k;
        p.Vt[hh * (NN * 2) + n * 2 + d2] = v;
        __syncthreads();
    }
    gbar(p.bar, 5, false);

    // ---- P5: attention (wave per head, 8 queries) + O-proj + BN partials ----
    {
        int wave = tid >> 6, lane = tid & 63;
        int row0 = blk * 8;
        for (int h = wave; h < NH; h += 4) {
            float qx[8], qy[8];
#pragma unroll
            for (int i = 0; i < 8; ++i) {
                float2 qq = ((const float2*)p.Q)[(row0 + i) * NH + h];
                qx[i] = qq.x;
                qy[i] = qq.y;
            }
            const float2* K2 = (const float2*)p.Kt + h * NN;
            const float2* V2 = (const float2*)p.Vt + h * NN;
            float sm[8], a0[8], a1[8];
#pragma unroll
            for (int i = 0; i < 8; ++i) { sm[i] = 0.f; a0[i] = 0.f; a1[i] = 0.f; }
#pragma unroll 2
            for (int it = 0; it < NN / 64; ++it) {
                float2 kk = K2[it * 64 + lane];
                float2 vv = V2[it * 64 + lane];
#pragma unroll
                for (int i = 0; i < 8; ++i) {
                    float pp = __expf(qx[i] * kk.x + qy[i] * kk.y);
                    sm[i] += pp;
                    a0[i] += pp * vv.x;
                    a1[i] += pp * vv.y;
                }
            }
#pragma unroll
            for (int i = 0; i < 8; ++i) {
#pragma unroll
                for (int off = 32; off > 0; off >>= 1) {
                    sm[i] += __shfl_xor(sm[i], off);
                    a0[i] += __shfl_xor(a0[i], off);
                    a1[i] += __shfl_xor(a1[i], off);
                }
                if (lane == 0) {
                    float rs = 1.f / sm[i];
                    shA[i * HSZ + 2 * h] = a0[i] * rs;
                    shA[i * HSZ + 2 * h + 1] = a1[i] * rs;
                }
            }
        }
        __syncthreads();
        // O-projection on the block's 8 rows (ao never left LDS; X stays in shB)
        int r = tid >> 5, j = tid & 31;
        float a = p.ob[j];
#pragma unroll
        for (int c = 0; c < HSZ; ++c) a += shA[r * HSZ + c] * p.ow[c * HSZ + j];
        shB[tid] = a;
        __syncthreads();
        if (tid < HSZ) {
            float s = 0.f, q = 0.f;
#pragma unroll
            for (int rr = 0; rr < 8; ++rr) {
                float v = shB[rr * HSZ + tid];
                s += v;
                q += v * v;
            }
            atomicAdd(&p.bnbuf[tid], s);
            atomicAdd(&p.bnbuf[HSZ + tid], q);
        }
    }
    gbar(p.bar, 6, false);

    // ---- P6: BN apply + MLP + scoring head + sigmoid (rows from LDS shB) ----
    if (tid < 8) {
        int row = tid;
        const float invN = 1.f / NN;
        float xr[HSZ];
#pragma unroll
        for (int i = 0; i < HSZ; ++i) {
            float mu = p.bnbuf[i] * invN;
            float var = p.bnbuf[HSZ + i] * invN - mu * mu;
            float rstd = rsqrtf(var + 1e-5f);
            xr[i] = (shB[row * HSZ + i] - mu) * rstd * p.bn_g[i] + p.bn_b[i];
        }
        float y[16];
#pragma unroll
        for (int j = 0; j < 16; ++j) {
            float a = p.m1b[j];
#pragma unroll
            for (int i = 0; i < HSZ; ++i) a += xr[i] * p.m1w[i * 16 + j];
            y[j] = fmaxf(a, 0.f);
        }
        float z[HSZ];
#pragma unroll
        for (int j = 0; j < HSZ; ++j) {
            float a = p.m2b[j];
#pragma unroll
            for (int i = 0; i < 16; ++i) a += y[i] * p.m2w[i * HSZ + j];
            z[j] = fmaxf(a, 0.f);
        }
        float a16[16];
#pragma unroll
        for (int j = 0; j < 16; ++j) {
            float a = p.b001[j];
#pragma unroll
            for (int i = 0; i < HSZ; ++i) a += z[i] * p.w001[i * 16 + j];
            a16[j] = a > 0.f ? a : 0.01f * a;
        }
        float b8[8];
#pragma unroll
        for (int j = 0; j < 8; ++j) {
            float a = p.b01[j];
#pragma unroll
            for (int i = 0; i < 16; ++i) a += a16[i] * p.w01[i * 8 + j];
            b8[j] = a > 0.f ? a : 0.01f * a;
        }
        float c4[4];
#pragma unroll
        for (int j = 0; j < 4; ++j) {
            float a = p.b1v[j];
#pragma unroll
            for (int i = 0; i < 8; ++i) a += b8[i] * p.w1v[i * 4 + j];
            c4[j] = a > 0.f ? a : 0.01f * a;
        }
        float d = p.b2v[0];
#pragma unroll
        for (int i = 0; i < 4; ++i) d += c4[i] * p.w2v[i];
        p.out[blk * 8 + row] = 1.f / (1.f + __expf(-d));
    }
}

extern "C" void kernel_launch(void* const* d_in, const int* in_sizes, int n_in,
                              void* d_out, int out_size, void* d_ws, size_t ws_size,
                              hipStream_t stream) {
    Params p;
    p.x = (const float*)d_in[0];
    p.src = (const int*)d_in[1];
    p.dst = (const int*)d_in[2];
    p.W1 = (const float*)d_in[3];
    p.al1 = (const float*)d_in[4];
    p.ar1 = (const float*)d_in[5];
    p.bg1 = (const float*)d_in[6];
    p.W2 = (const float*)d_in[7];
    p.al2 = (const float*)d_in[8];
    p.ar2 = (const float*)d_in[9];
    p.bg2 = (const float*)d_in[10];
    p.qw = (const float*)d_in[11];
    p.qb = (const float*)d_in[12];
    p.kw = (const float*)d_in[13];
    p.kb = (const float*)d_in[14];
    p.vw = (const float*)d_in[15];
    p.vb = (const float*)d_in[16];
    p.ow = (const float*)d_in[17];
    p.ob = (const float*)d_in[18];
    p.bn_g = (const float*)d_in[19];
    p.bn_b = (const float*)d_in[20];
    p.m1w = (const float*)d_in[21];
    p.m1b = (const float*)d_in[22];
    p.m2w = (const float*)d_in[23];
    p.m2b = (const float*)d_in[24];
    p.w001 = (const float*)d_in[25];
    p.b001 = (const float*)d_in[26];
    p.w01 = (const float*)d_in[27];
    p.b01 = (const float*)d_in[28];
    p.w1v = (const float*)d_in[29];
    p.b1v = (const float*)d_in[30];
    p.w2v = (const float*)d_in[31];
    p.b2v = (const float*)d_in[32];
    p.E = in_sizes[1];

    float* ws = (float*)d_ws;
    p.feat = ws;                       // NN*32
    p.el = p.feat + NN * HSZ;          // NN*16
    p.er = p.el + NN * NH;             // NN*16
    p.ssumA = p.er + NN * NH;          // NN*16 ┐ zeroed as one
    p.accA = p.ssumA + NN * NH;        // NN*32 │ contiguous
    p.ssumB = p.accA + NN * HSZ;       // NN*16 │ region in P0
    p.accB = p.ssumB + NN * NH;        // NN*32 │
    p.bnbuf = p.accB + NN * HSZ;       // 64    ┘
    p.Q = p.bnbuf + 64;                // NN*32
    p.Kt = p.Q + NN * HSZ;             // NN*32
    p.Vt = p.Kt + NN * HSZ;            // NN*32
    p.bar = (int*)(p.Vt + NN * HSZ);   // 3 × 128B-spaced slots
    p.out = (float*)d_out;

    mega<<<dim3(NBLK), dim3(NTHR), 0, stream>>>(p);
}

// Round 7
// 263.913 us; speedup vs baseline: 1.8836x; 1.4838x over previous
//
#include <hip/hip_runtime.h>
#include <math.h>

#define NN 2048
#define NH 16
#define HSZ 32
#define INF_ 256
#define NBLK 256
#define NTHR 256
#define NTOT (NBLK * NTHR)
#define DOOR_MAGIC 0x1357bd1

// bar slot indices (ints, 128B apart): 16 group counters, root, flag, doorbell
#define BAR_ROOT 512
#define BAR_FLAG 544
#define BAR_DOOR 576

struct Params {
    const float *x, *W1, *al1, *ar1, *bg1, *W2, *al2, *ar2, *bg2;
    const float *qw, *qb, *kw, *kb, *vw, *vb, *ow, *ob;
    const float *bn_g, *bn_b, *m1w, *m1b, *m2w, *m2b;
    const float *w001, *b001, *w01, *b01, *w1v, *b1v, *w2v, *b2v;
    const int *src, *dst;
    float *feat, *el, *er, *ssumA, *accA, *ssumB, *accB, *bnbuf, *KV, *out;
    int *bar;
    int E;
};

// agent-scope relaxed atomic store: sc1 write that bypasses L2 (never dirties
// it) and is visible at the coherence point once vmcnt retires (__syncthreads
// drains vmcnt per wave -> no release fence / buffer_wbl2 needed anywhere).
__device__ __forceinline__ void st_agent(float* p, float v) {
    __hip_atomic_store(p, v, __ATOMIC_RELAXED, __HIP_MEMORY_SCOPE_AGENT);
}

// Fence-free grid barrier: monotonic 16x16 arrival tree (relaxed far-adds,
// no same-address 256-chain, no wbl2), relaxed poll on a separate line,
// then a per-wave ACQUIRE fence (buffer_inv only -> plain cached loads are
// safe afterwards; also drops stale 0xAA lines left by the ws poison fill).
__device__ __forceinline__ void gbar(int* bar, int phase, bool first) {
    __syncthreads();  // drains vmcnt(0) per wave: all sc1 stores agent-visible
    if (threadIdx.x == 0) {
        if (first) {
            while (__hip_atomic_load(&bar[BAR_DOOR], __ATOMIC_RELAXED,
                                     __HIP_MEMORY_SCOPE_AGENT) != DOOR_MAGIC)
                __builtin_amdgcn_s_sleep(1);
        }
        int g = blockIdx.x & 15;
        int old = __hip_atomic_fetch_add(&bar[g * 32], 1, __ATOMIC_RELAXED,
                                         __HIP_MEMORY_SCOPE_AGENT);
        if (old == phase * 16 - 1) {  // last of my 16-block group this phase
            int r = __hip_atomic_fetch_add(&bar[BAR_ROOT], 1, __ATOMIC_RELAXED,
                                           __HIP_MEMORY_SCOPE_AGENT);
            if (r == phase * 16 - 1)
                __hip_atomic_store(&bar[BAR_FLAG], phase, __ATOMIC_RELAXED,
                                   __HIP_MEMORY_SCOPE_AGENT);
        }
        while (__hip_atomic_load(&bar[BAR_FLAG], __ATOMIC_RELAXED,
                                 __HIP_MEMORY_SCOPE_AGENT) < phase)
            __builtin_amdgcn_s_sleep(1);
    }
    __syncthreads();
    __builtin_amdgcn_fence(__ATOMIC_ACQUIRE, "agent");  // per-wave buffer_inv
}

// edge softmax-accumulate: thread per (edge,head), grid-stride, plain loads
__device__ __forceinline__ void edge_phase(const int* __restrict__ src,
                                           const int* __restrict__ dst,
                                           const float* __restrict__ el,
                                           const float* __restrict__ er,
                                           const float* __restrict__ feat,
                                           float* __restrict__ ssum,
                                           float* __restrict__ acc, int E, int gtid) {
    int EH = E * NH;
    for (int i = gtid; i < EH; i += NTOT) {
        int e = i >> 4, h = i & 15;
        int s = src[e], d = dst[e];
        float v = el[s * NH + h] + er[d * NH + h];
        v = v > 0.f ? v : 0.2f * v;
        float ex = __expf(v);
        float2 f = ((const float2*)feat)[s * NH + h];
        atomicAdd(&ssum[d * NH + h], ex);
        atomicAdd(&acc[(d * NH + h) * 2 + 0], ex * f.x);
        atomicAdd(&acc[(d * NH + h) * 2 + 1], ex * f.y);
    }
}

__global__ void __launch_bounds__(NTHR, 1) mega(Params p) {
    __shared__ float shA[256];
    __shared__ float shB[256];
    __shared__ float shQ[256];
    const int tid = threadIdx.x;
    const int blk = blockIdx.x;
    const int gtid = blk * NTHR + tid;
    const int r = tid >> 5, j = tid & 31;
    const int row0 = blk * 8;

    // ---- barrier init: zero counters, then RELEASE doorbell (one wbl2, once)
    if (blk == 0 && tid == 0) {
        for (int g = 0; g < 16; ++g)
            __hip_atomic_store(&p.bar[g * 32], 0, __ATOMIC_RELAXED,
                               __HIP_MEMORY_SCOPE_AGENT);
        __hip_atomic_store(&p.bar[BAR_ROOT], 0, __ATOMIC_RELAXED,
                           __HIP_MEMORY_SCOPE_AGENT);
        __hip_atomic_store(&p.bar[BAR_FLAG], 0, __ATOMIC_RELAXED,
                           __HIP_MEMORY_SCOPE_AGENT);
        __hip_atomic_store(&p.bar[BAR_DOOR], DOOR_MAGIC, __ATOMIC_RELEASE,
                           __HIP_MEMORY_SCOPE_AGENT);
    }

    // ---- P0: zero accumulators (sc1) + GAT1 feats (feat/el/er via sc1) ----
    {
        float* z = p.ssumA;
        const int ztot = NN * 96 + 64;
        for (int i = gtid; i < ztot; i += NTOT) st_agent(&z[i], 0.f);
    }
    for (int rr = 0; rr < 8; ++rr) {
        int n = row0 + rr;
        shA[tid] = p.x[(size_t)n * INF_ + tid];
        __syncthreads();
        float a = 0.f;
#pragma unroll
        for (int kk = 0; kk < 32; ++kk) {
            int k = (tid >> 5) * 32 + kk;
            a += shA[k] * p.W1[k * HSZ + j];
        }
        shB[tid] = a;
        __syncthreads();
        if (tid < HSZ) {
            float s = 0.f;
#pragma unroll
            for (int q = 0; q < 8; ++q) s += shB[q * 32 + tid];
            st_agent(&p.feat[n * HSZ + tid], s);
            shA[tid] = s;
        }
        __syncthreads();
        if (tid < NH) {
            st_agent(&p.el[n * NH + tid],
                     shA[2 * tid] * p.al1[2 * tid] + shA[2 * tid + 1] * p.al1[2 * tid + 1]);
        } else if (tid < 2 * NH) {
            int hh = tid - NH;
            st_agent(&p.er[n * NH + hh],
                     shA[2 * hh] * p.ar1[2 * hh] + shA[2 * hh + 1] * p.ar1[2 * hh + 1]);
        }
        __syncthreads();
    }
    gbar(p.bar, 1, true);

    // ---- P1: edge accumulate, layer 1 ----
    edge_phase(p.src, p.dst, p.el, p.er, p.feat, p.ssumA, p.accA, p.E, gtid);
    gbar(p.bar, 2, false);

    // ---- P2: normalize h1 -> GAT2 feats (sc1 out) ----
    {
        int n = row0 + r;
        shA[tid] = p.accA[n * HSZ + j] / p.ssumA[n * NH + (j >> 1)] + p.bg1[j];
        __syncthreads();
        float a = 0.f;
#pragma unroll
        for (int c = 0; c < HSZ; ++c) a += shA[r * HSZ + c] * p.W2[c * HSZ + j];
        shB[tid] = a;
        st_agent(&p.feat[row0 * HSZ + tid], a);
        __syncthreads();
        if (tid < 128) {
            int rr = tid >> 4, hh = tid & 15;
            st_agent(&p.el[(row0 + rr) * NH + hh],
                     shB[rr * HSZ + 2 * hh] * p.al2[2 * hh] +
                         shB[rr * HSZ + 2 * hh + 1] * p.al2[2 * hh + 1]);
        } else {
            int t = tid - 128, rr = t >> 4, hh = t & 15;
            st_agent(&p.er[(row0 + rr) * NH + hh],
                     shB[rr * HSZ + 2 * hh] * p.ar2[2 * hh] +
                         shB[rr * HSZ + 2 * hh + 1] * p.ar2[2 * hh + 1]);
        }
    }
    gbar(p.bar, 3, false);

    // ---- P3: edge accumulate, layer 2 ----
    edge_phase(p.src, p.dst, p.el, p.er, p.feat, p.ssumB, p.accB, p.E, gtid);
    gbar(p.bar, 4, false);

    // ---- P4: h2 -> QKV. Q stays in LDS (block-local); K,V packed float4 ----
    {
        int n = row0 + r;
        shA[tid] = p.accB[n * HSZ + j] / p.ssumB[n * NH + (j >> 1)] + p.bg2[j];
        __syncthreads();
        float q = p.qb[j], k = p.kb[j], v = p.vb[j];
#pragma unroll
        for (int c = 0; c < HSZ; ++c) {
            float hv = shA[r * HSZ + c];
            q += hv * p.qw[c * HSZ + j];
            k += hv * p.kw[c * HSZ + j];
            v += hv * p.vw[c * HSZ + j];
        }
        shQ[tid] = q * 0.70710678118654752f;
        int hh = j >> 1, d2 = j & 1;
        st_agent(&p.KV[(hh * NN + n) * 4 + d2], k);
        st_agent(&p.KV[(hh * NN + n) * 4 + 2 + d2], v);
    }
    gbar(p.bar, 5, false);

    // ---- P5: attention (wave per head, block's 8 queries from shQ) +
    //          O-projection + BN partial sums. KV via plain cached float4. ----
    {
        int wave = tid >> 6, lane = tid & 63;
        for (int h = wave; h < NH; h += 4) {
            float qx[8], qy[8];
#pragma unroll
            for (int i = 0; i < 8; ++i) {
                qx[i] = shQ[i * HSZ + 2 * h];
                qy[i] = shQ[i * HSZ + 2 * h + 1];
            }
            const float4* KV4 = (const float4*)p.KV + h * NN;
            float sm[8], a0[8], a1[8];
#pragma unroll
            for (int i = 0; i < 8; ++i) { sm[i] = 0.f; a0[i] = 0.f; a1[i] = 0.f; }
#pragma unroll 2
            for (int it = 0; it < NN / 64; ++it) {
                float4 kv = KV4[it * 64 + lane];
#pragma unroll
                for (int i = 0; i < 8; ++i) {
                    float pp = __expf(qx[i] * kv.x + qy[i] * kv.y);
                    sm[i] += pp;
                    a0[i] += pp * kv.z;
                    a1[i] += pp * kv.w;
                }
            }
#pragma unroll
            for (int i = 0; i < 8; ++i) {
#pragma unroll
                for (int off = 32; off > 0; off >>= 1) {
                    sm[i] += __shfl_xor(sm[i], off);
                    a0[i] += __shfl_xor(a0[i], off);
                    a1[i] += __shfl_xor(a1[i], off);
                }
                if (lane == 0) {
                    float rs = 1.f / sm[i];
                    shA[i * HSZ + 2 * h] = a0[i] * rs;
                    shA[i * HSZ + 2 * h + 1] = a1[i] * rs;
                }
            }
        }
        __syncthreads();
        float a = p.ob[j];
#pragma unroll
        for (int c = 0; c < HSZ; ++c) a += shA[r * HSZ + c] * p.ow[c * HSZ + j];
        shB[tid] = a;  // X rows stay in LDS for P6
        __syncthreads();
        if (tid < HSZ) {
            float s = 0.f, q = 0.f;
#pragma unroll
            for (int rr = 0; rr < 8; ++rr) {
                float v = shB[rr * HSZ + tid];
                s += v;
                q += v * v;
            }
            atomicAdd(&p.bnbuf[tid], s);
            atomicAdd(&p.bnbuf[HSZ + tid], q);
        }
    }
    gbar(p.bar, 6, false);

    // ---- P6: BN apply + MLP + scoring head + sigmoid (rows from LDS shB) ----
    if (tid < 8) {
        int row = tid;
        const float invN = 1.f / NN;
        float xr[HSZ];
#pragma unroll
        for (int i = 0; i < HSZ; ++i) {
            float mu = p.bnbuf[i] * invN;
            float var = p.bnbuf[HSZ + i] * invN - mu * mu;
            float rstd = rsqrtf(var + 1e-5f);
            xr[i] = (shB[row * HSZ + i] - mu) * rstd * p.bn_g[i] + p.bn_b[i];
        }
        float y[16];
#pragma unroll
        for (int jj = 0; jj < 16; ++jj) {
            float a = p.m1b[jj];
#pragma unroll
            for (int i = 0; i < HSZ; ++i) a += xr[i] * p.m1w[i * 16 + jj];
            y[jj] = fmaxf(a, 0.f);
        }
        float z[HSZ];
#pragma unroll
        for (int jj = 0; jj < HSZ; ++jj) {
            float a = p.m2b[jj];
#pragma unroll
            for (int i = 0; i < 16; ++i) a += y[i] * p.m2w[i * HSZ + jj];
            z[jj] = fmaxf(a, 0.f);
        }
        float a16[16];
#pragma unroll
        for (int jj = 0; jj < 16; ++jj) {
            float a = p.b001[jj];
#pragma unroll
            for (int i = 0; i < HSZ; ++i) a += z[i] * p.w001[i * 16 + jj];
            a16[jj] = a > 0.f ? a : 0.01f * a;
        }
        float b8[8];
#pragma unroll
        for (int jj = 0; jj < 8; ++jj) {
            float a = p.b01[jj];
#pragma unroll
            for (int i = 0; i < 16; ++i) a += a16[i] * p.w01[i * 8 + jj];
            b8[jj] = a > 0.f ? a : 0.01f * a;
        }
        float c4[4];
#pragma unroll
        for (int jj = 0; jj < 4; ++jj) {
            float a = p.b1v[jj];
#pragma unroll
            for (int i = 0; i < 8; ++i) a += b8[i] * p.w1v[i * 4 + jj];
            c4[jj] = a > 0.f ? a : 0.01f * a;
        }
        float d = p.b2v[0];
#pragma unroll
        for (int i = 0; i < 4; ++i) d += c4[i] * p.w2v[i];
        p.out[row0 + row] = 1.f / (1.f + __expf(-d));
    }
}

extern "C" void kernel_launch(void* const* d_in, const int* in_sizes, int n_in,
                              void* d_out, int out_size, void* d_ws, size_t ws_size,
                              hipStream_t stream) {
    Params p;
    p.x = (const float*)d_in[0];
    p.src = (const int*)d_in[1];
    p.dst = (const int*)d_in[2];
    p.W1 = (const float*)d_in[3];
    p.al1 = (const float*)d_in[4];
    p.ar1 = (const float*)d_in[5];
    p.bg1 = (const float*)d_in[6];
    p.W2 = (const float*)d_in[7];
    p.al2 = (const float*)d_in[8];
    p.ar2 = (const float*)d_in[9];
    p.bg2 = (const float*)d_in[10];
    p.qw = (const float*)d_in[11];
    p.qb = (const float*)d_in[12];
    p.kw = (const float*)d_in[13];
    p.kb = (const float*)d_in[14];
    p.vw = (const float*)d_in[15];
    p.vb = (const float*)d_in[16];
    p.ow = (const float*)d_in[17];
    p.ob = (const float*)d_in[18];
    p.bn_g = (const float*)d_in[19];
    p.bn_b = (const float*)d_in[20];
    p.m1w = (const float*)d_in[21];
    p.m1b = (const float*)d_in[22];
    p.m2w = (const float*)d_in[23];
    p.m2b = (const float*)d_in[24];
    p.w001 = (const float*)d_in[25];
    p.b001 = (const float*)d_in[26];
    p.w01 = (const float*)d_in[27];
    p.b01 = (const float*)d_in[28];
    p.w1v = (const float*)d_in[29];
    p.b1v = (const float*)d_in[30];
    p.w2v = (const float*)d_in[31];
    p.b2v = (const float*)d_in[32];
    p.E = in_sizes[1];

    float* ws = (float*)d_ws;
    p.feat = ws;                       // NN*32
    p.el = p.feat + NN * HSZ;          // NN*16
    p.er = p.el + NN * NH;             // NN*16
    p.ssumA = p.er + NN * NH;          // NN*16 ┐ zeroed as one
    p.accA = p.ssumA + NN * NH;        // NN*32 │ contiguous
    p.ssumB = p.accA + NN * HSZ;       // NN*16 │ region in P0
    p.accB = p.ssumB + NN * NH;        // NN*32 │
    p.bnbuf = p.accB + NN * HSZ;       // 64    ┘
    p.KV = p.bnbuf + 64;               // NH*NN*4 (k0,k1,v0,v1 per key)
    p.bar = (int*)(p.KV + NH * NN * 4);  // 577 ints, 128B-spaced slots
    p.out = (float*)d_out;

    mega<<<dim3(NBLK), dim3(NTHR), 0, stream>>>(p);
}